// Round 10
// baseline (508.417 us; speedup 1.0000x reference)
//
#include <hip/hip_runtime.h>

#define D 128
#define NBUCKET 3125          // (N=50000)/16 groups of 16 dst nodes
#define CHUNK 32768           // edges per sort block

typedef unsigned int uint;
typedef unsigned short ushort;
typedef unsigned long long ull;

typedef __attribute__((ext_vector_type(8))) short bf16x8;
typedef __attribute__((ext_vector_type(4))) float f32x4;

__device__ inline ushort f2bf(float f) {
    uint u = __float_as_uint(f);
    uint r = (u + 0x7fffu + ((u >> 16) & 1u)) >> 16;   // RNE
    return (ushort)r;
}

__device__ inline float bflo(uint g) { return __uint_as_float(g << 16); }
__device__ inline float bfhi(uint g) { return __uint_as_float(g & 0xffff0000u); }

// ============ atomic-free CSR build: bucket sort on dst>>4 ==================
// (R7: partitioned global atomics neutral; R9: 4B vs 8B fetch-add neutral ->
// returning global atomics are op-limited ~21G/s. This build uses only LDS
// atomics + plain stores.)

// hist per block of CHUNK edges -> ghist[b*NBUCKET + d]
__global__ __launch_bounds__(256) void k_rhist(const int* __restrict__ col,
                                               int* __restrict__ ghist, int e) {
    __shared__ int hist[NBUCKET];
    int t = threadIdx.x;
    for (int d = t; d < NBUCKET; d += 256) hist[d] = 0;
    __syncthreads();
    int i0 = blockIdx.x * CHUNK;
    int i1 = min(i0 + CHUNK, e);
    for (int i = i0 + t; i < i1; i += 256)
        atomicAdd(&hist[col[i] >> 4], 1);
    __syncthreads();
    int* gh = ghist + (size_t)blockIdx.x * NBUCKET;
    for (int d = t; d < NBUCKET; d += 256) gh[d] = hist[d];
}

// per-digit totals across blocks
__global__ __launch_bounds__(256) void k_rscanA(const int* __restrict__ ghist,
                                                int* __restrict__ dtot, int nb) {
    int d = blockIdx.x * 256 + threadIdx.x;
    if (d >= NBUCKET) return;
    int s = 0;
    for (int b = 0; b < nb; ++b) s += ghist[(size_t)b * NBUCKET + d];
    dtot[d] = s;
}

// exclusive scan of 3125 digit totals -> gptr; also gptr[NBUCKET]=e, ptr[n]=e
__global__ __launch_bounds__(256) void k_rscanB(const int* __restrict__ dtot,
                                                int* __restrict__ gptr,
                                                int* __restrict__ ptr, int n, int e) {
    int t = threadIdx.x;
    int lane = t & 63, wid = t >> 6;
    int local[13];
    int lsum = 0;
#pragma unroll
    for (int j = 0; j < 13; ++j) {
        int d = t * 13 + j;
        local[j] = (d < NBUCKET) ? dtot[d] : 0;
        lsum += local[j];
    }
    int s = lsum;
#pragma unroll
    for (int off = 1; off < 64; off <<= 1) {
        int v = __shfl_up(s, off);
        if (lane >= off) s += v;
    }
    __shared__ int wsum[4];
    if (lane == 63) wsum[wid] = s;
    __syncthreads();
    int wo = 0;
    for (int w2 = 0; w2 < wid; ++w2) wo += wsum[w2];
    s += wo;
    int run = s - lsum;          // exclusive base for this thread's digits
#pragma unroll
    for (int j = 0; j < 13; ++j) {
        int d = t * 13 + j;
        if (d < NBUCKET) { gptr[d] = run; run += local[j]; }
    }
    if (t == 255) { gptr[NBUCKET] = e; ptr[n] = e; }
}

// convert ghist counts -> per-(block,digit) scatter bases
__global__ __launch_bounds__(256) void k_rscanC(const int* __restrict__ gptr,
                                                int* __restrict__ ghist, int nb) {
    int d = blockIdx.x * 256 + threadIdx.x;
    if (d >= NBUCKET) return;
    int run = gptr[d];
    for (int b = 0; b < nb; ++b) {
        size_t idx = (size_t)b * NBUCKET + d;
        int v = ghist[idx];
        ghist[idx] = run;
        run += v;
    }
}

// scatter edges into bucket-sorted rec array (LDS cursors, plain stores)
__global__ __launch_bounds__(256) void k_rscatter(const int* __restrict__ row,
                                                  const int* __restrict__ col,
                                                  const float* __restrict__ w,
                                                  const int* __restrict__ ghist,
                                                  ull* __restrict__ rec, int e) {
    __shared__ int cur[NBUCKET];
    int t = threadIdx.x;
    const int* gh = ghist + (size_t)blockIdx.x * NBUCKET;
    for (int d = t; d < NBUCKET; d += 256) cur[d] = gh[d];
    __syncthreads();
    int i0 = blockIdx.x * CHUNK;
    int i1 = min(i0 + CHUNK, e);
    for (int i = i0 + t; i < i1; i += 256) {
        int dst = col[i];
        int src = row[i];
        uint wb = __float_as_uint(w[i]);
        int pos = atomicAdd(&cur[dst >> 4], 1);
        rec[pos] = ((ull)(uint)dst << 48) | ((ull)(uint)src << 32) | (ull)wb;
    }
}

// split each 16-node group in LDS: emit ptr, dinv, csr{src,w}
__global__ __launch_bounds__(256) void k_finish(const ull* __restrict__ rec,
                                                const int* __restrict__ gptr,
                                                int* __restrict__ ptr,
                                                float* __restrict__ dinv,
                                                int2* __restrict__ csr, int n) {
    __shared__ int   cnt[16];
    __shared__ float ws16[16];
    __shared__ int   cur[16];
    int g = blockIdx.x;
    int t = threadIdx.x;
    int lo = gptr[g], hi = gptr[g + 1];
    if (t < 16) { cnt[t] = 0; ws16[t] = 0.0f; }
    __syncthreads();
    for (int i = lo + t; i < hi; i += 256) {
        ull r = rec[i];
        int d4 = (int)((r >> 48) & 15);
        atomicAdd(&cnt[d4], 1);
        atomicAdd(&ws16[d4], __uint_as_float((uint)r));
    }
    __syncthreads();
    if (t == 0) {
        int run = lo;
        for (int j = 0; j < 16; ++j) {
            int node = g * 16 + j;
            ptr[node] = run;
            cur[j] = run;
            dinv[node] = rsqrtf(fmaxf(1.0f + ws16[j], 1e-12f));
            run += cnt[j];
        }
    }
    __syncthreads();
    for (int i = lo + t; i < hi; i += 256) {
        ull r = rec[i];
        int d4 = (int)((r >> 48) & 15);
        int pos = atomicAdd(&cur[d4], 1);
        csr[pos] = make_int2((int)((r >> 32) & 0xffff), (int)(uint)r);
    }
}

// ---------------- MFMA GEMM: xws[n][d] = dinv[n] * (h[n] @ W^T), bf16 out ---

#define LDW 136

__global__ __launch_bounds__(256) void k_gemm(const float* __restrict__ h,
                                              const float* __restrict__ W,
                                              const float* __restrict__ dinv,
                                              ushort* __restrict__ xw, int n) {
    __shared__ ushort Wl[128 * LDW];
    __shared__ ushort Hl[64 * LDW];
    __shared__ float  sdv[64];

    const int t   = threadIdx.x;
    const int gn0 = blockIdx.x * 64;

    if (t < 64) {
        int gn = gn0 + t;
        sdv[t] = (gn < n) ? dinv[gn] : 0.0f;
    }
    for (int i = t; i < 4096; i += 256) {
        int d  = i >> 5;
        int k4 = (i & 31) * 4;
        float4 wv = *(const float4*)(W + d * D + k4);
        ushort4 p;
        p.x = f2bf(wv.x); p.y = f2bf(wv.y); p.z = f2bf(wv.z); p.w = f2bf(wv.w);
        *(ushort4*)(Wl + d * LDW + k4) = p;
    }
    for (int i = t; i < 2048; i += 256) {
        int r  = i >> 5;
        int k4 = (i & 31) * 4;
        int gn = gn0 + r;
        float4 hv = (gn < n) ? *(const float4*)(h + (size_t)gn * D + k4)
                             : make_float4(0.f, 0.f, 0.f, 0.f);
        ushort4 p;
        p.x = f2bf(hv.x); p.y = f2bf(hv.y); p.z = f2bf(hv.z); p.w = f2bf(hv.w);
        *(ushort4*)(Hl + r * LDW + k4) = p;
    }
    __syncthreads();

    const int wave  = t >> 6;
    const int lane  = t & 63;
    const int quad  = lane >> 4;
    const int l15   = lane & 15;
    const int nbase = wave * 32;

    f32x4 acc[4][2];
#pragma unroll
    for (int mt = 0; mt < 4; ++mt)
#pragma unroll
        for (int nt = 0; nt < 2; ++nt) acc[mt][nt] = (f32x4)(0.0f);

#pragma unroll
    for (int kc = 0; kc < 4; ++kc) {
        int ko = kc * 32 + quad * 8;
        bf16x8 a[4], b[2];
#pragma unroll
        for (int mt = 0; mt < 4; ++mt)
            a[mt] = *(const bf16x8*)(Hl + (mt * 16 + l15) * LDW + ko);
#pragma unroll
        for (int nt = 0; nt < 2; ++nt)
            b[nt] = *(const bf16x8*)(Wl + (nbase + nt * 16 + l15) * LDW + ko);
#pragma unroll
        for (int mt = 0; mt < 4; ++mt)
#pragma unroll
            for (int nt = 0; nt < 2; ++nt)
                acc[mt][nt] = __builtin_amdgcn_mfma_f32_16x16x32_bf16(
                    a[mt], b[nt], acc[mt][nt], 0, 0, 0);
    }
    __syncthreads();

    // scale by dinv[row] then bounce through LDS for coalesced stores
#pragma unroll
    for (int mt = 0; mt < 4; ++mt)
#pragma unroll
        for (int r = 0; r < 4; ++r) {
            int rowl = mt * 16 + quad * 4 + r;
            float dv = sdv[rowl];
#pragma unroll
            for (int nt = 0; nt < 2; ++nt)
                Hl[rowl * LDW + nbase + nt * 16 + l15] = f2bf(acc[mt][nt][r] * dv);
        }
    __syncthreads();

    for (int i = t; i < 1024; i += 256) {
        int r = i >> 4, seg = i & 15;
        int gn = gn0 + r;
        if (gn < n) {
            uint4 v = *(const uint4*)(Hl + r * LDW + seg * 8);
            *(uint4*)(xw + (size_t)gn * D + seg * 8) = v;
        }
    }
}

// ---------------- fused pull-aggregate + bias + LN + ReLU + residual --------
// out[c] = b + dinv[c] * (sum_e w_e * xws[src_e] + xws[c]);  xws = dinv*h@W^T.
// One wave per node; halves stride-2 interleave; at the measured ~3.5 TB/s
// random-gather fabric ceiling (R7/R8: deeper MLP neutral).

__global__ __launch_bounds__(256) void k_pull_ln(const ushort* __restrict__ xw,
                                                 const int* __restrict__ ptr,
                                                 const int2* __restrict__ csr,
                                                 const float* __restrict__ dinv,
                                                 const float* __restrict__ bias,
                                                 const float* __restrict__ gamma,
                                                 const float* __restrict__ beta,
                                                 const float* __restrict__ identity,
                                                 float* __restrict__ hout,
                                                 int n, int relu) {
    int node = blockIdx.x * 4 + (threadIdx.x >> 6);
    if (node >= n) return;
    int lane = threadIdx.x & 63;
    int half = lane >> 5;
    int l    = lane & 31;
    int o    = l * 4;

    float a0 = 0.f, a1 = 0.f, a2 = 0.f, a3 = 0.f;

    int ebeg = ptr[node];
    int eend = ptr[node + 1];
    int e = ebeg + half;
    for (; e + 6 < eend; e += 8) {
        int2 eA = csr[e], eB = csr[e + 2], eC = csr[e + 4], eD2 = csr[e + 6];
        uint2 gA = *(const uint2*)(xw + (size_t)eA.x * D + o);
        uint2 gB = *(const uint2*)(xw + (size_t)eB.x * D + o);
        uint2 gC = *(const uint2*)(xw + (size_t)eC.x * D + o);
        uint2 gD = *(const uint2*)(xw + (size_t)eD2.x * D + o);
        float nA = __int_as_float(eA.y), nB = __int_as_float(eB.y);
        float nC = __int_as_float(eC.y), nD = __int_as_float(eD2.y);
        a0 += nA * bflo(gA.x) + nB * bflo(gB.x);
        a1 += nA * bfhi(gA.x) + nB * bfhi(gB.x);
        a2 += nA * bflo(gA.y) + nB * bflo(gB.y);
        a3 += nA * bfhi(gA.y) + nB * bfhi(gB.y);
        a0 += nC * bflo(gC.x) + nD * bflo(gD.x);
        a1 += nC * bfhi(gC.x) + nD * bfhi(gD.x);
        a2 += nC * bflo(gC.y) + nD * bflo(gD.y);
        a3 += nC * bfhi(gC.y) + nD * bfhi(gD.y);
    }
    for (; e < eend; e += 2) {
        int2 eA = csr[e];
        uint2 gA = *(const uint2*)(xw + (size_t)eA.x * D + o);
        float nA = __int_as_float(eA.y);
        a0 += nA * bflo(gA.x);
        a1 += nA * bfhi(gA.x);
        a2 += nA * bflo(gA.y);
        a3 += nA * bfhi(gA.y);
    }

    a0 += __shfl_xor(a0, 32);
    a1 += __shfl_xor(a1, 32);
    a2 += __shfl_xor(a2, 32);
    a3 += __shfl_xor(a3, 32);

    float di = dinv[node];
    uint2 ps = *(const uint2*)(xw + (size_t)node * D + o);   // xws row (pre-scaled)
    float4 bb = *(const float4*)(bias + o);
    a0 = bb.x + di * (bflo(ps.x) + a0);
    a1 = bb.y + di * (bfhi(ps.x) + a1);
    a2 = bb.z + di * (bflo(ps.y) + a2);
    a3 = bb.w + di * (bfhi(ps.y) + a3);

    // LayerNorm over 128 features: reduce across 32 lanes (halves identical)
    float s = (a0 + a1) + (a2 + a3);
#pragma unroll
    for (int off = 16; off; off >>= 1) s += __shfl_xor(s, off);
    float mu = s * (1.0f / 128.0f);
    float d0 = a0 - mu, d1 = a1 - mu, d2 = a2 - mu, d3 = a3 - mu;
    float vs = (d0 * d0 + d1 * d1) + (d2 * d2 + d3 * d3);
#pragma unroll
    for (int off = 16; off; off >>= 1) vs += __shfl_xor(vs, off);
    float rs = rsqrtf(vs * (1.0f / 128.0f) + 1e-5f);

    float4 g  = *(const float4*)(gamma + o);
    float4 b2 = *(const float4*)(beta + o);
    float4 id = *(const float4*)(identity + (size_t)node * D + o);
    float o0 = d0 * rs * g.x + b2.x;
    float o1 = d1 * rs * g.y + b2.y;
    float o2 = d2 * rs * g.z + b2.z;
    float o3 = d3 * rs * g.w + b2.w;
    if (relu) {
        o0 = fmaxf(o0, 0.0f); o1 = fmaxf(o1, 0.0f);
        o2 = fmaxf(o2, 0.0f); o3 = fmaxf(o3, 0.0f);
    }
    if (half == 0)
        *(float4*)(hout + (size_t)node * D + o) =
            make_float4(o0 + id.x, o1 + id.y, o2 + id.z, o3 + id.w);
}

// ---------------- launch ----------------

extern "C" void kernel_launch(void* const* d_in, const int* in_sizes, int n_in,
                              void* d_out, int out_size, void* d_ws, size_t ws_size,
                              hipStream_t stream) {
    const float* x      = (const float*)d_in[0];
    const int*   ei     = (const int*)d_in[1];
    const float* ew     = (const float*)d_in[2];
    const float* Ws     = (const float*)d_in[3];
    const float* bs     = (const float*)d_in[4];
    const float* gammas = (const float*)d_in[5];
    const float* betas  = (const float*)d_in[6];
    float* out = (float*)d_out;

    const int N = in_sizes[0] / D;
    const int E = in_sizes[2];
    const int* row = ei;
    const int* col = ei + E;

    const int nbSort = (E + CHUNK - 1) / CHUNK;

    // workspace layout. recA (8B*E) aliases buf1 (4B*N*D): recA is dead after
    // k_finish, before buf1's first write (layer-1 pull output).
    char* w8 = (char*)d_ws;
    size_t unionBytes = sizeof(float) * (size_t)N * D;   // 25.6MB >= 8*E
    if (sizeof(ull) * (size_t)E > unionBytes) unionBytes = sizeof(ull) * (size_t)E;
    ull*   recA  = (ull*)w8;
    float* buf1  = (float*)w8;  w8 += unionBytes;
    int2*  csr   = (int2*)w8;   w8 += sizeof(int2) * E;
    int*   ghist = (int*)w8;    w8 += sizeof(int) * (size_t)(nbSort + 1) * NBUCKET;
    int*   dtot  = (int*)w8;    w8 += sizeof(int) * NBUCKET;
    int*   gptr  = (int*)w8;    w8 += sizeof(int) * (NBUCKET + 1);
    int*   ptr   = (int*)w8;    w8 += sizeof(int) * (N + 1);
    float* dinv  = (float*)w8;  w8 += sizeof(float) * N;
    ushort* xwb  = (ushort*)w8; w8 += sizeof(ushort) * (size_t)N * D;

    dim3 blk(256);
    int gBkt  = (NBUCKET + 255) / 256;
    int gGemm = (N + 63) / 64;
    int gPull = (N + 3) / 4;
    int gFin  = (N + 15) / 16;

    k_rhist<<<nbSort, blk, 0, stream>>>(col, ghist, E);
    k_rscanA<<<gBkt, blk, 0, stream>>>(ghist, dtot, nbSort);
    k_rscanB<<<1, blk, 0, stream>>>(dtot, gptr, ptr, N, E);
    k_rscanC<<<gBkt, blk, 0, stream>>>(gptr, ghist, nbSort);
    k_rscatter<<<nbSort, blk, 0, stream>>>(row, col, ew, ghist, recA, E);
    k_finish<<<gFin, blk, 0, stream>>>(recA, gptr, ptr, dinv, csr, N);

    // layer 0: h = x -> out
    k_gemm<<<gGemm, blk, 0, stream>>>(x, Ws, dinv, xwb, N);
    k_pull_ln<<<gPull, blk, 0, stream>>>(xwb, ptr, csr, dinv,
                                         bs, gammas, betas, x, out, N, 1);
    // layer 1: h = out -> buf1
    k_gemm<<<gGemm, blk, 0, stream>>>(out, Ws + 16384, dinv, xwb, N);
    k_pull_ln<<<gPull, blk, 0, stream>>>(xwb, ptr, csr, dinv,
                                         bs + D, gammas + D, betas + D, out, buf1, N, 1);
    // layer 2: h = buf1 -> out
    k_gemm<<<gGemm, blk, 0, stream>>>(buf1, Ws + 32768, dinv, xwb, N);
    k_pull_ln<<<gPull, blk, 0, stream>>>(xwb, ptr, csr, dinv,
                                         bs + 2 * D, gammas + 2 * D, betas + 2 * D,
                                         buf1, out, N, 0);
}

// Round 11
// 450.889 us; speedup vs baseline: 1.1276x; 1.1276x over previous
//
#include <hip/hip_runtime.h>

#define D 128
#define NBUCKET 3125          // (N=50000)/16 groups of 16 dst nodes
#define CHUNK 4096            // edges per sort block (R10: 32768 -> 1.9% occupancy)

typedef unsigned int uint;
typedef unsigned short ushort;
typedef unsigned long long ull;

typedef __attribute__((ext_vector_type(8))) short bf16x8;
typedef __attribute__((ext_vector_type(4))) float f32x4;

__device__ inline ushort f2bf(float f) {
    uint u = __float_as_uint(f);
    uint r = (u + 0x7fffu + ((u >> 16) & 1u)) >> 16;   // RNE
    return (ushort)r;
}

__device__ inline float bflo(uint g) { return __uint_as_float(g << 16); }
__device__ inline float bfhi(uint g) { return __uint_as_float(g & 0xffff0000u); }

// ============ atomic-free CSR build: bucket sort on dst>>4 ==================

__global__ __launch_bounds__(256) void k_rhist(const int* __restrict__ col,
                                               int* __restrict__ ghist, int e) {
    __shared__ int hist[NBUCKET];
    int t = threadIdx.x;
    for (int d = t; d < NBUCKET; d += 256) hist[d] = 0;
    __syncthreads();
    int i0 = blockIdx.x * CHUNK;
    int i1 = min(i0 + CHUNK, e);
    for (int i = i0 + t; i < i1; i += 256)
        atomicAdd(&hist[col[i] >> 4], 1);
    __syncthreads();
    int* gh = ghist + (size_t)blockIdx.x * NBUCKET;
    for (int d = t; d < NBUCKET; d += 256) gh[d] = hist[d];
}

// per-digit totals across blocks (8x unrolled independent loads)
__global__ __launch_bounds__(256) void k_rscanA(const int* __restrict__ ghist,
                                                int* __restrict__ dtot, int nb) {
    int d = blockIdx.x * 256 + threadIdx.x;
    if (d >= NBUCKET) return;
    int s = 0;
    int b = 0;
    for (; b + 7 < nb; b += 8) {
        const int* p = ghist + (size_t)b * NBUCKET + d;
        int v0 = p[0];
        int v1 = p[NBUCKET];
        int v2 = p[2 * NBUCKET];
        int v3 = p[3 * NBUCKET];
        int v4 = p[4 * NBUCKET];
        int v5 = p[5 * NBUCKET];
        int v6 = p[6 * NBUCKET];
        int v7 = p[7 * NBUCKET];
        s += ((v0 + v1) + (v2 + v3)) + ((v4 + v5) + (v6 + v7));
    }
    for (; b < nb; ++b) s += ghist[(size_t)b * NBUCKET + d];
    dtot[d] = s;
}

// exclusive scan of 3125 digit totals -> gptr; also gptr[NBUCKET]=e, ptr[n]=e
__global__ __launch_bounds__(256) void k_rscanB(const int* __restrict__ dtot,
                                                int* __restrict__ gptr,
                                                int* __restrict__ ptr, int n, int e) {
    int t = threadIdx.x;
    int lane = t & 63, wid = t >> 6;
    int local[13];
    int lsum = 0;
#pragma unroll
    for (int j = 0; j < 13; ++j) {
        int d = t * 13 + j;
        local[j] = (d < NBUCKET) ? dtot[d] : 0;
        lsum += local[j];
    }
    int s = lsum;
#pragma unroll
    for (int off = 1; off < 64; off <<= 1) {
        int v = __shfl_up(s, off);
        if (lane >= off) s += v;
    }
    __shared__ int wsum[4];
    if (lane == 63) wsum[wid] = s;
    __syncthreads();
    int wo = 0;
    for (int w2 = 0; w2 < wid; ++w2) wo += wsum[w2];
    s += wo;
    int run = s - lsum;          // exclusive base for this thread's digits
#pragma unroll
    for (int j = 0; j < 13; ++j) {
        int d = t * 13 + j;
        if (d < NBUCKET) { gptr[d] = run; run += local[j]; }
    }
    if (t == 255) { gptr[NBUCKET] = e; ptr[n] = e; }
}

// counts -> per-(block,digit) scatter bases (8x unrolled loads in flight)
__global__ __launch_bounds__(256) void k_rscanC(const int* __restrict__ gptr,
                                                int* __restrict__ ghist, int nb) {
    int d = blockIdx.x * 256 + threadIdx.x;
    if (d >= NBUCKET) return;
    int run = gptr[d];
    int b = 0;
    for (; b + 7 < nb; b += 8) {
        int* p = ghist + (size_t)b * NBUCKET + d;
        int v0 = p[0];
        int v1 = p[NBUCKET];
        int v2 = p[2 * NBUCKET];
        int v3 = p[3 * NBUCKET];
        int v4 = p[4 * NBUCKET];
        int v5 = p[5 * NBUCKET];
        int v6 = p[6 * NBUCKET];
        int v7 = p[7 * NBUCKET];
        p[0] = run;               run += v0;
        p[NBUCKET] = run;         run += v1;
        p[2 * NBUCKET] = run;     run += v2;
        p[3 * NBUCKET] = run;     run += v3;
        p[4 * NBUCKET] = run;     run += v4;
        p[5 * NBUCKET] = run;     run += v5;
        p[6 * NBUCKET] = run;     run += v6;
        p[7 * NBUCKET] = run;     run += v7;
    }
    for (; b < nb; ++b) {
        size_t idx = (size_t)b * NBUCKET + d;
        int v = ghist[idx];
        ghist[idx] = run;
        run += v;
    }
}

// scatter edges into bucket-sorted rec array (LDS cursors, plain stores)
__global__ __launch_bounds__(256) void k_rscatter(const int* __restrict__ row,
                                                  const int* __restrict__ col,
                                                  const float* __restrict__ w,
                                                  const int* __restrict__ ghist,
                                                  ull* __restrict__ rec, int e) {
    __shared__ int cur[NBUCKET];
    int t = threadIdx.x;
    const int* gh = ghist + (size_t)blockIdx.x * NBUCKET;
    for (int d = t; d < NBUCKET; d += 256) cur[d] = gh[d];
    __syncthreads();
    int i0 = blockIdx.x * CHUNK;
    int i1 = min(i0 + CHUNK, e);
    for (int i = i0 + t; i < i1; i += 256) {
        int dst = col[i];
        int src = row[i];
        uint wb = __float_as_uint(w[i]);
        int pos = atomicAdd(&cur[dst >> 4], 1);
        rec[pos] = ((ull)(uint)dst << 48) | ((ull)(uint)src << 32) | (ull)wb;
    }
}

// split each 16-node group in LDS: emit ptr, dinv, csr{src,w}
__global__ __launch_bounds__(256) void k_finish(const ull* __restrict__ rec,
                                                const int* __restrict__ gptr,
                                                int* __restrict__ ptr,
                                                float* __restrict__ dinv,
                                                int2* __restrict__ csr, int n) {
    __shared__ int   cnt[16];
    __shared__ float ws16[16];
    __shared__ int   cur[16];
    int g = blockIdx.x;
    int t = threadIdx.x;
    int lo = gptr[g], hi = gptr[g + 1];
    if (t < 16) { cnt[t] = 0; ws16[t] = 0.0f; }
    __syncthreads();
    for (int i = lo + t; i < hi; i += 256) {
        ull r = rec[i];
        int d4 = (int)((r >> 48) & 15);
        atomicAdd(&cnt[d4], 1);
        atomicAdd(&ws16[d4], __uint_as_float((uint)r));
    }
    __syncthreads();
    if (t == 0) {
        int run = lo;
        for (int j = 0; j < 16; ++j) {
            int node = g * 16 + j;
            ptr[node] = run;
            cur[j] = run;
            dinv[node] = rsqrtf(fmaxf(1.0f + ws16[j], 1e-12f));
            run += cnt[j];
        }
    }
    __syncthreads();
    for (int i = lo + t; i < hi; i += 256) {
        ull r = rec[i];
        int d4 = (int)((r >> 48) & 15);
        int pos = atomicAdd(&cur[d4], 1);
        csr[pos] = make_int2((int)((r >> 32) & 0xffff), (int)(uint)r);
    }
}

// ---------------- MFMA GEMM: xws[n][d] = dinv[n] * (h[n] @ W^T), bf16 out ---

#define LDW 136

__global__ __launch_bounds__(256) void k_gemm(const float* __restrict__ h,
                                              const float* __restrict__ W,
                                              const float* __restrict__ dinv,
                                              ushort* __restrict__ xw, int n) {
    __shared__ ushort Wl[128 * LDW];
    __shared__ ushort Hl[64 * LDW];
    __shared__ float  sdv[64];

    const int t   = threadIdx.x;
    const int gn0 = blockIdx.x * 64;

    if (t < 64) {
        int gn = gn0 + t;
        sdv[t] = (gn < n) ? dinv[gn] : 0.0f;
    }
    for (int i = t; i < 4096; i += 256) {
        int d  = i >> 5;
        int k4 = (i & 31) * 4;
        float4 wv = *(const float4*)(W + d * D + k4);
        ushort4 p;
        p.x = f2bf(wv.x); p.y = f2bf(wv.y); p.z = f2bf(wv.z); p.w = f2bf(wv.w);
        *(ushort4*)(Wl + d * LDW + k4) = p;
    }
    for (int i = t; i < 2048; i += 256) {
        int r  = i >> 5;
        int k4 = (i & 31) * 4;
        int gn = gn0 + r;
        float4 hv = (gn < n) ? *(const float4*)(h + (size_t)gn * D + k4)
                             : make_float4(0.f, 0.f, 0.f, 0.f);
        ushort4 p;
        p.x = f2bf(hv.x); p.y = f2bf(hv.y); p.z = f2bf(hv.z); p.w = f2bf(hv.w);
        *(ushort4*)(Hl + r * LDW + k4) = p;
    }
    __syncthreads();

    const int wave  = t >> 6;
    const int lane  = t & 63;
    const int quad  = lane >> 4;
    const int l15   = lane & 15;
    const int nbase = wave * 32;

    f32x4 acc[4][2];
#pragma unroll
    for (int mt = 0; mt < 4; ++mt)
#pragma unroll
        for (int nt = 0; nt < 2; ++nt) acc[mt][nt] = (f32x4)(0.0f);

#pragma unroll
    for (int kc = 0; kc < 4; ++kc) {
        int ko = kc * 32 + quad * 8;
        bf16x8 a[4], b[2];
#pragma unroll
        for (int mt = 0; mt < 4; ++mt)
            a[mt] = *(const bf16x8*)(Hl + (mt * 16 + l15) * LDW + ko);
#pragma unroll
        for (int nt = 0; nt < 2; ++nt)
            b[nt] = *(const bf16x8*)(Wl + (nbase + nt * 16 + l15) * LDW + ko);
#pragma unroll
        for (int mt = 0; mt < 4; ++mt)
#pragma unroll
            for (int nt = 0; nt < 2; ++nt)
                acc[mt][nt] = __builtin_amdgcn_mfma_f32_16x16x32_bf16(
                    a[mt], b[nt], acc[mt][nt], 0, 0, 0);
    }
    __syncthreads();

    // scale by dinv[row] then bounce through LDS for coalesced stores
#pragma unroll
    for (int mt = 0; mt < 4; ++mt)
#pragma unroll
        for (int r = 0; r < 4; ++r) {
            int rowl = mt * 16 + quad * 4 + r;
            float dv = sdv[rowl];
#pragma unroll
            for (int nt = 0; nt < 2; ++nt)
                Hl[rowl * LDW + nbase + nt * 16 + l15] = f2bf(acc[mt][nt][r] * dv);
        }
    __syncthreads();

    for (int i = t; i < 1024; i += 256) {
        int r = i >> 4, seg = i & 15;
        int gn = gn0 + r;
        if (gn < n) {
            uint4 v = *(const uint4*)(Hl + r * LDW + seg * 8);
            *(uint4*)(xw + (size_t)gn * D + seg * 8) = v;
        }
    }
}

// ---------------- fused pull-aggregate + bias + LN + ReLU + residual --------
// out[c] = b + dinv[c] * (sum_e w_e * xws[src_e] + xws[c]);  xws = dinv*h@W^T.
// At the measured ~3.5 TB/s random-gather fabric ceiling (R7/R8).

__global__ __launch_bounds__(256) void k_pull_ln(const ushort* __restrict__ xw,
                                                 const int* __restrict__ ptr,
                                                 const int2* __restrict__ csr,
                                                 const float* __restrict__ dinv,
                                                 const float* __restrict__ bias,
                                                 const float* __restrict__ gamma,
                                                 const float* __restrict__ beta,
                                                 const float* __restrict__ identity,
                                                 float* __restrict__ hout,
                                                 int n, int relu) {
    int node = blockIdx.x * 4 + (threadIdx.x >> 6);
    if (node >= n) return;
    int lane = threadIdx.x & 63;
    int half = lane >> 5;
    int l    = lane & 31;
    int o    = l * 4;

    float a0 = 0.f, a1 = 0.f, a2 = 0.f, a3 = 0.f;

    int ebeg = ptr[node];
    int eend = ptr[node + 1];
    int e = ebeg + half;
    for (; e + 6 < eend; e += 8) {
        int2 eA = csr[e], eB = csr[e + 2], eC = csr[e + 4], eD2 = csr[e + 6];
        uint2 gA = *(const uint2*)(xw + (size_t)eA.x * D + o);
        uint2 gB = *(const uint2*)(xw + (size_t)eB.x * D + o);
        uint2 gC = *(const uint2*)(xw + (size_t)eC.x * D + o);
        uint2 gD = *(const uint2*)(xw + (size_t)eD2.x * D + o);
        float nA = __int_as_float(eA.y), nB = __int_as_float(eB.y);
        float nC = __int_as_float(eC.y), nD = __int_as_float(eD2.y);
        a0 += nA * bflo(gA.x) + nB * bflo(gB.x);
        a1 += nA * bfhi(gA.x) + nB * bfhi(gB.x);
        a2 += nA * bflo(gA.y) + nB * bflo(gB.y);
        a3 += nA * bfhi(gA.y) + nB * bfhi(gB.y);
        a0 += nC * bflo(gC.x) + nD * bflo(gD.x);
        a1 += nC * bfhi(gC.x) + nD * bfhi(gD.x);
        a2 += nC * bflo(gC.y) + nD * bflo(gD.y);
        a3 += nC * bfhi(gC.y) + nD * bfhi(gD.y);
    }
    for (; e < eend; e += 2) {
        int2 eA = csr[e];
        uint2 gA = *(const uint2*)(xw + (size_t)eA.x * D + o);
        float nA = __int_as_float(eA.y);
        a0 += nA * bflo(gA.x);
        a1 += nA * bfhi(gA.x);
        a2 += nA * bflo(gA.y);
        a3 += nA * bfhi(gA.y);
    }

    a0 += __shfl_xor(a0, 32);
    a1 += __shfl_xor(a1, 32);
    a2 += __shfl_xor(a2, 32);
    a3 += __shfl_xor(a3, 32);

    float di = dinv[node];
    uint2 ps = *(const uint2*)(xw + (size_t)node * D + o);   // xws row (pre-scaled)
    float4 bb = *(const float4*)(bias + o);
    a0 = bb.x + di * (bflo(ps.x) + a0);
    a1 = bb.y + di * (bfhi(ps.x) + a1);
    a2 = bb.z + di * (bflo(ps.y) + a2);
    a3 = bb.w + di * (bfhi(ps.y) + a3);

    // LayerNorm over 128 features: reduce across 32 lanes (halves identical)
    float s = (a0 + a1) + (a2 + a3);
#pragma unroll
    for (int off = 16; off; off >>= 1) s += __shfl_xor(s, off);
    float mu = s * (1.0f / 128.0f);
    float d0 = a0 - mu, d1 = a1 - mu, d2 = a2 - mu, d3 = a3 - mu;
    float vs = (d0 * d0 + d1 * d1) + (d2 * d2 + d3 * d3);
#pragma unroll
    for (int off = 16; off; off >>= 1) vs += __shfl_xor(vs, off);
    float rs = rsqrtf(vs * (1.0f / 128.0f) + 1e-5f);

    float4 g  = *(const float4*)(gamma + o);
    float4 b2 = *(const float4*)(beta + o);
    float4 id = *(const float4*)(identity + (size_t)node * D + o);
    float o0 = d0 * rs * g.x + b2.x;
    float o1 = d1 * rs * g.y + b2.y;
    float o2 = d2 * rs * g.z + b2.z;
    float o3 = d3 * rs * g.w + b2.w;
    if (relu) {
        o0 = fmaxf(o0, 0.0f); o1 = fmaxf(o1, 0.0f);
        o2 = fmaxf(o2, 0.0f); o3 = fmaxf(o3, 0.0f);
    }
    if (half == 0)
        *(float4*)(hout + (size_t)node * D + o) =
            make_float4(o0 + id.x, o1 + id.y, o2 + id.z, o3 + id.w);
}

// ---------------- launch ----------------

extern "C" void kernel_launch(void* const* d_in, const int* in_sizes, int n_in,
                              void* d_out, int out_size, void* d_ws, size_t ws_size,
                              hipStream_t stream) {
    const float* x      = (const float*)d_in[0];
    const int*   ei     = (const int*)d_in[1];
    const float* ew     = (const float*)d_in[2];
    const float* Ws     = (const float*)d_in[3];
    const float* bs     = (const float*)d_in[4];
    const float* gammas = (const float*)d_in[5];
    const float* betas  = (const float*)d_in[6];
    float* out = (float*)d_out;

    const int N = in_sizes[0] / D;
    const int E = in_sizes[2];
    const int* row = ei;
    const int* col = ei + E;

    const int nbSort = (E + CHUNK - 1) / CHUNK;

    // workspace layout. recA (8B*E) aliases buf1 (4B*N*D): recA is dead after
    // k_finish, before buf1's first write (layer-1 pull output).
    char* w8 = (char*)d_ws;
    size_t unionBytes = sizeof(float) * (size_t)N * D;   // 25.6MB >= 8*E
    if (sizeof(ull) * (size_t)E > unionBytes) unionBytes = sizeof(ull) * (size_t)E;
    ull*   recA  = (ull*)w8;
    float* buf1  = (float*)w8;  w8 += unionBytes;
    int2*  csr   = (int2*)w8;   w8 += sizeof(int2) * E;
    int*   ghist = (int*)w8;    w8 += sizeof(int) * (size_t)(nbSort + 1) * NBUCKET;
    int*   dtot  = (int*)w8;    w8 += sizeof(int) * NBUCKET;
    int*   gptr  = (int*)w8;    w8 += sizeof(int) * (NBUCKET + 1);
    int*   ptr   = (int*)w8;    w8 += sizeof(int) * (N + 1);
    float* dinv  = (float*)w8;  w8 += sizeof(float) * N;
    ushort* xwb  = (ushort*)w8; w8 += sizeof(ushort) * (size_t)N * D;

    dim3 blk(256);
    int gBkt  = (NBUCKET + 255) / 256;
    int gGemm = (N + 63) / 64;
    int gPull = (N + 3) / 4;
    int gFin  = (N + 15) / 16;

    k_rhist<<<nbSort, blk, 0, stream>>>(col, ghist, E);
    k_rscanA<<<gBkt, blk, 0, stream>>>(ghist, dtot, nbSort);
    k_rscanB<<<1, blk, 0, stream>>>(dtot, gptr, ptr, N, E);
    k_rscanC<<<gBkt, blk, 0, stream>>>(gptr, ghist, nbSort);
    k_rscatter<<<nbSort, blk, 0, stream>>>(row, col, ew, ghist, recA, E);
    k_finish<<<gFin, blk, 0, stream>>>(recA, gptr, ptr, dinv, csr, N);

    // layer 0: h = x -> out
    k_gemm<<<gGemm, blk, 0, stream>>>(x, Ws, dinv, xwb, N);
    k_pull_ln<<<gPull, blk, 0, stream>>>(xwb, ptr, csr, dinv,
                                         bs, gammas, betas, x, out, N, 1);
    // layer 1: h = out -> buf1
    k_gemm<<<gGemm, blk, 0, stream>>>(out, Ws + 16384, dinv, xwb, N);
    k_pull_ln<<<gPull, blk, 0, stream>>>(xwb, ptr, csr, dinv,
                                         bs + D, gammas + D, betas + D, out, buf1, N, 1);
    // layer 2: h = buf1 -> out
    k_gemm<<<gGemm, blk, 0, stream>>>(buf1, Ws + 32768, dinv, xwb, N);
    k_pull_ln<<<gPull, blk, 0, stream>>>(xwb, ptr, csr, dinv,
                                         bs + 2 * D, gammas + 2 * D, betas + 2 * D,
                                         buf1, out, N, 0);
}